// Round 1
// baseline (2610.489 us; speedup 1.0000x reference)
//
#include <hip/hip_runtime.h>
#include <cfloat>

#define BB 8
#define NN 1024
#define CC 256
#define KK 4096
#define SN 11
#define BNC (BB*NN*CC)

// ---------------------------------------------------------------------------
// proj_w transpose: pwT[j*C + c] = pw[c*C + j]
__global__ void transpose_pw(const float* __restrict__ pw, float* __restrict__ pwT) {
    int j = blockIdx.x;
    int c = threadIdx.x;
    pwT[j * CC + c] = pw[c * CC + j];
}

// ---------------------------------------------------------------------------
// embedding = base @ proj_w.T + b ; also embT [C][K] and e_sq[k]
// grid K/16 blocks, 256 threads; thread = output channel c
__global__ __launch_bounds__(256) void embed_kernel(
    const float* __restrict__ base, const float* __restrict__ pwT,
    const float* __restrict__ pb, float* __restrict__ emb,
    float* __restrict__ embT, float* __restrict__ esq) {
    __shared__ float bs[16][CC];
    __shared__ float red[256];
    int k0 = blockIdx.x * 16;
    int t = threadIdx.x;
    for (int i = t; i < 16 * CC; i += 256) {
        bs[i >> 8][i & 255] = base[k0 * CC + i];
    }
    __syncthreads();
    float acc[16];
#pragma unroll
    for (int m = 0; m < 16; ++m) acc[m] = 0.f;
    for (int j = 0; j < CC; ++j) {
        float w = pwT[j * CC + t];
#pragma unroll
        for (int m = 0; m < 16; ++m) acc[m] += bs[m][j] * w;
    }
    __syncthreads();  // done reading bs as base rows
    float bias = pb[t];
    for (int m = 0; m < 16; ++m) {
        float v = acc[m] + bias;
        emb[(k0 + m) * CC + t] = v;
        bs[m][t] = v;  // stage for transposed write
        red[t] = v * v;
        __syncthreads();
        for (int s = 128; s > 0; s >>= 1) {
            if (t < s) red[t] += red[t + s];
            __syncthreads();
        }
        if (t == 0) esq[k0 + m] = red[0];
        __syncthreads();
    }
    // write embT rows: thread t owns channel c=t, 16 consecutive k (full 64B lines)
#pragma unroll
    for (int g = 0; g < 4; ++g) {
        float4 vv = make_float4(bs[4 * g + 0][t], bs[4 * g + 1][t],
                                bs[4 * g + 2][t], bs[4 * g + 3][t]);
        *(float4*)&embT[(size_t)t * KK + k0 + 4 * g] = vv;
    }
}

// ---------------------------------------------------------------------------
// mean-pool f_rest over groups: q[b*pn+p][c], grid = B*pn, block = 64 (float4/c)
__global__ void pool_kernel(const float* __restrict__ fr, float* __restrict__ q, int pn) {
    int r = blockIdx.x;
    int b = r / pn, p = r % pn;
    int g = NN / pn;
    int c4 = threadIdx.x;  // 0..63
    const float4* src = (const float4*)(fr + ((size_t)b * NN + (size_t)p * g) * CC) + c4;
    float4 s = make_float4(0.f, 0.f, 0.f, 0.f);
    for (int i = 0; i < g; ++i) {
        float4 v = src[(size_t)i * 64];
        s.x += v.x; s.y += v.y; s.z += v.z; s.w += v.w;
    }
    float inv = 1.f / (float)g;
    s.x *= inv; s.y *= inv; s.z *= inv; s.w *= inv;
    ((float4*)(q + (size_t)r * CC))[c4] = s;
}

// ---------------------------------------------------------------------------
// distances + partial argmin.
// block: 256 threads, handles 16 rows x (passes_per*256) codes.
// grid: (ceil(R/16), ks); pass p covers codes [p*256, p*256+256)
__global__ __launch_bounds__(256) void dist_kernel(
    const float* __restrict__ q, const float* __restrict__ embT,
    const float* __restrict__ esq, int R, int passes_per,
    float* __restrict__ pval, int* __restrict__ pidx) {
    __shared__ float qs[16][CC];
    __shared__ float rv[256];
    __shared__ int ri[256];
    int t = threadIdx.x;
    int r0 = blockIdx.x * 16;
    int sp = blockIdx.y;
    for (int i = t; i < 16 * 64; i += 256) {
        int m = i >> 6, c4 = i & 63;
        int r = r0 + m;
        float4 v = (r < R) ? ((const float4*)(q + (size_t)r * CC))[c4]
                           : make_float4(0.f, 0.f, 0.f, 0.f);
        *(float4*)&qs[m][c4 * 4] = v;
    }
    __syncthreads();
    float bv[16];
    int bi[16];
#pragma unroll
    for (int m = 0; m < 16; ++m) { bv[m] = FLT_MAX; bi[m] = 0x7fffffff; }
    for (int pp = 0; pp < passes_per; ++pp) {
        int pass = sp * passes_per + pp;
        int k = pass * 256 + t;
        float acc[16];
#pragma unroll
        for (int m = 0; m < 16; ++m) acc[m] = 0.f;
        for (int c4 = 0; c4 < 64; ++c4) {
            float e0 = embT[(size_t)(4 * c4 + 0) * KK + k];
            float e1 = embT[(size_t)(4 * c4 + 1) * KK + k];
            float e2 = embT[(size_t)(4 * c4 + 2) * KK + k];
            float e3 = embT[(size_t)(4 * c4 + 3) * KK + k];
#pragma unroll
            for (int m = 0; m < 16; ++m) {
                float4 qv = *(const float4*)&qs[m][c4 * 4];
                acc[m] += qv.x * e0 + qv.y * e1 + qv.z * e2 + qv.w * e3;
            }
        }
        float es = esq[k];
#pragma unroll
        for (int m = 0; m < 16; ++m) {
            float s = es - 2.f * acc[m];
            if (s < bv[m]) { bv[m] = s; bi[m] = k; }  // strict <: earliest k wins
        }
    }
    // per-row cross-thread argmin reduce (lexicographic: value, then index)
    for (int m = 0; m < 16; ++m) {
        rv[t] = bv[m];
        ri[t] = bi[m];
        __syncthreads();
        for (int s = 128; s > 0; s >>= 1) {
            if (t < s) {
                float v2 = rv[t + s]; int i2 = ri[t + s];
                if (v2 < rv[t] || (v2 == rv[t] && i2 < ri[t])) { rv[t] = v2; ri[t] = i2; }
            }
            __syncthreads();
        }
        if (t == 0 && r0 + m < R) {
            pval[(r0 + m) * 16 + sp] = rv[0];
            pidx[(r0 + m) * 16 + sp] = ri[0];
        }
        __syncthreads();
    }
}

// ---------------------------------------------------------------------------
__global__ void combine_kernel(const float* __restrict__ pval, const int* __restrict__ pidx,
                               int R, int ks, int* __restrict__ idx) {
    int r = blockIdx.x * 256 + threadIdx.x;
    if (r >= R) return;
    float bv = pval[r * 16];
    int bi = pidx[r * 16];
    for (int s = 1; s < ks; ++s) {
        float v = pval[r * 16 + s];
        int i = pidx[r * 16 + s];
        if (v < bv || (v == bv && i < bi)) { bv = v; bi = i; }
    }
    idx[r] = bi;
}

// ---------------------------------------------------------------------------
// gather + linear interp + f_hat/f_rest update + per-block loss partial
// grid = B*N blocks, 256 threads (thread = channel)
__global__ __launch_bounds__(256) void update_kernel(
    const float* __restrict__ emb, const int* __restrict__ idx,
    const float* __restrict__ f, float* __restrict__ fhat,
    float* __restrict__ frest, float* __restrict__ parts, int pn) {
    int bn = blockIdx.x;
    int b = bn >> 10, n = bn & 1023;
    int t = threadIdx.x;
    float s = (n + 0.5f) * ((float)pn * (1.0f / 1024.0f)) - 0.5f;
    if (s < 0.f) s = 0.f;
    int i0 = (int)s;
    float w = s - (float)i0;
    int i1 = min(i0 + 1, pn - 1);
    int k0 = idx[b * pn + i0];
    int k1 = idx[b * pn + i1];
    float e0 = emb[(size_t)k0 * CC + t];
    float e1 = emb[(size_t)k1 * CC + t];
    float h = (1.f - w) * e0 + w * e1;
    size_t o = (size_t)bn * CC + t;
    float fh = fhat[o] + h;
    fhat[o] = fh;
    frest[o] -= h;
    float d = fh - f[o];
    float sq = d * d;
    for (int off = 32; off > 0; off >>= 1) sq += __shfl_down(sq, off);
    __shared__ float wred[4];
    if ((t & 63) == 0) wred[t >> 6] = sq;
    __syncthreads();
    if (t == 0) parts[bn] = wred[0] + wred[1] + wred[2] + wred[3];
}

// deterministic loss partial reduce: 8192 -> 1
__global__ void reduce_loss(const float* __restrict__ parts, float* __restrict__ loss_s) {
    __shared__ float red[256];
    int t = threadIdx.x;
    float s = 0.f;
    for (int i = t; i < BB * NN; i += 256) s += parts[i];
    red[t] = s;
    __syncthreads();
    for (int k = 128; k > 0; k >>= 1) {
        if (t < k) red[t] += red[t + k];
        __syncthreads();
    }
    if (t == 0) *loss_s = red[0];
}

__global__ void finalize_kernel(const float* __restrict__ loss, float* __restrict__ out) {
    float cs = 0.f;
    for (int s = 0; s < SN; ++s) cs += loss[s];
    float mean_sum = cs / (float)BNC;
    out[BNC] = 0.25f * mean_sum / (float)SN;
    out[BNC + 1] = mean_sum / (float)SN;
}

// ---------------------------------------------------------------------------
extern "C" void kernel_launch(void* const* d_in, const int* in_sizes, int n_in,
                              void* d_out, int out_size, void* d_ws, size_t ws_size,
                              hipStream_t stream) {
    const float* f    = (const float*)d_in[0];  // [B,N,C]
    const float* base = (const float*)d_in[1];  // [K,C]
    const float* pw   = (const float*)d_in[2];  // [C,C]
    const float* pb   = (const float*)d_in[3];  // [C]
    float* out = (float*)d_out;                 // [B*N*C] f_hat + commit + qlat

    float* emb   = (float*)d_ws;        // K*C
    float* embT  = emb + KK * CC;       // C*K
    float* esq   = embT + CC * KK;      // K
    float* pwT   = esq + KK;            // C*C
    float* frest = pwT + CC * CC;       // BNC
    float* q     = frest + BNC;         // B*1024*C (max)
    float* pval  = q + BB * 1024 * CC;  // 8192*16
    float* loss  = pval + 8192 * 16;    // SN
    float* parts = loss + SN;           // 8192
    int* idxb    = (int*)(parts + BB * NN);  // 8192
    int* pidx    = idxb + 8192;              // 8192*16

    hipMemsetAsync(out, 0, (size_t)BNC * sizeof(float), stream);
    hipMemcpyAsync(frest, f, (size_t)BNC * sizeof(float), hipMemcpyDeviceToDevice, stream);

    transpose_pw<<<CC, CC, 0, stream>>>(pw, pwT);
    embed_kernel<<<KK / 16, 256, 0, stream>>>(base, pwT, pb, emb, embT, esq);

    for (int sidx = 0; sidx < SN; ++sidx) {
        int pn = 1 << sidx;
        int R = BB * pn;
        pool_kernel<<<R, 64, 0, stream>>>(frest, q, pn);
        int rb = (R + 15) / 16;
        int ks = KK / R;
        if (ks > 16) ks = 16;
        if (ks < 1) ks = 1;
        int passes_per = 16 / ks;
        dim3 grid(rb, ks);
        dist_kernel<<<grid, 256, 0, stream>>>(q, embT, esq, R, passes_per, pval, pidx);
        combine_kernel<<<(R + 255) / 256, 256, 0, stream>>>(pval, pidx, R, ks, idxb);
        update_kernel<<<BB * NN, 256, 0, stream>>>(emb, idxb, f, out, frest, parts, pn);
        reduce_loss<<<1, 256, 0, stream>>>(parts, loss + sidx);
    }
    finalize_kernel<<<1, 1, 0, stream>>>(loss, out);
}

// Round 2
// 1120.713 us; speedup vs baseline: 2.3293x; 2.3293x over previous
//
#include <hip/hip_runtime.h>
#include <cfloat>

#define BB 8
#define NN 1024
#define CC 256
#define KK 4096
#define SN 11
#define BNC (BB*NN*CC)
#define RMAX 8192

typedef __attribute__((ext_vector_type(8))) short short8;
typedef __attribute__((ext_vector_type(4))) float f32x4;

__device__ __forceinline__ ushort f2bf(float f) {
    union { float f; unsigned u; } x; x.f = f;
    unsigned r = (x.u + 0x7fffu + ((x.u >> 16) & 1u)) >> 16;
    return (ushort)r;
}
__device__ __forceinline__ float bf2f(ushort b) {
    union { float f; unsigned u; } x; x.u = ((unsigned)b) << 16;
    return x.f;
}
__device__ __forceinline__ void split3(float v, ushort& h, ushort& m, ushort& l) {
    h = f2bf(v);
    float fh = bf2f(h);
    m = f2bf(v - fh);
    float fm = bf2f(m);
    l = f2bf(v - fh - fm);
}

// ---------------------------------------------------------------------------
__global__ void transpose_pw(const float* __restrict__ pw, float* __restrict__ pwT) {
    int j = blockIdx.x;
    int c = threadIdx.x;
    pwT[j * CC + c] = pw[c * CC + j];
}

// ---------------------------------------------------------------------------
// embedding = base @ proj_w.T + b ; f32 emb, 3-way bf16 splits, e_sq
__global__ __launch_bounds__(256) void embed_kernel(
    const float* __restrict__ base, const float* __restrict__ pwT,
    const float* __restrict__ pb, float* __restrict__ emb,
    ushort* __restrict__ eh, ushort* __restrict__ em, ushort* __restrict__ el,
    float* __restrict__ esq) {
    __shared__ float bs[16][CC];
    __shared__ float red[256];
    int k0 = blockIdx.x * 16;
    int t = threadIdx.x;
    for (int i = t; i < 16 * CC; i += 256) bs[i >> 8][i & 255] = base[k0 * CC + i];
    __syncthreads();
    float acc[16];
#pragma unroll
    for (int m = 0; m < 16; ++m) acc[m] = 0.f;
    for (int j = 0; j < CC; ++j) {
        float w = pwT[j * CC + t];
#pragma unroll
        for (int m = 0; m < 16; ++m) acc[m] += bs[m][j] * w;
    }
    float bias = pb[t];
    for (int m = 0; m < 16; ++m) {
        float v = acc[m] + bias;
        int o = (k0 + m) * CC + t;
        emb[o] = v;
        ushort h, md, lo;
        split3(v, h, md, lo);
        eh[o] = h; em[o] = md; el[o] = lo;
        red[t] = v * v;
        __syncthreads();
        for (int s = 128; s > 0; s >>= 1) {
            if (t < s) red[t] += red[t + s];
            __syncthreads();
        }
        if (t == 0) esq[k0 + m] = red[0];
        __syncthreads();
    }
}

// ---------------------------------------------------------------------------
// mean-pool f_rest + 3-way bf16 split. grid = rb*64 rows (zero-padded), 64 thr
__global__ void pool_split(const float* __restrict__ fr,
                           ushort* __restrict__ qh, ushort* __restrict__ qm,
                           ushort* __restrict__ ql, int pn, int R) {
    int r = blockIdx.x;
    int c4 = threadIdx.x;  // 0..63
    float4 sv = make_float4(0.f, 0.f, 0.f, 0.f);
    if (r < R) {
        int b = r / pn, p = r - b * pn;
        int g = NN / pn;
        const float4* src = (const float4*)(fr + ((size_t)b * NN + (size_t)p * g) * CC) + c4;
        for (int i = 0; i < g; ++i) {
            float4 v = src[(size_t)i * 64];
            sv.x += v.x; sv.y += v.y; sv.z += v.z; sv.w += v.w;
        }
        float inv = 1.f / (float)g;
        sv.x *= inv; sv.y *= inv; sv.z *= inv; sv.w *= inv;
    }
    ushort4 H, M, L;
    split3(sv.x, H.x, M.x, L.x);
    split3(sv.y, H.y, M.y, L.y);
    split3(sv.z, H.z, M.z, L.z);
    split3(sv.w, H.w, M.w, L.w);
    size_t o = (size_t)r * CC + 4 * c4;
    *(ushort4*)&qh[o] = H;
    *(ushort4*)&qm[o] = M;
    *(ushort4*)&ql[o] = L;
}

// ---------------------------------------------------------------------------
// MFMA distance + fused per-row argmin.
// Block tile: 64 rows x 128 codes, BK=64, 4 waves (wave w: cols w*32..w*32+31).
// f32 emulated via 3-way bf16 split: 6 product passes (hh,hm,mh,hl,mm,lh).
// LDS tiles staged via global_load_lds with XOR-(row&7) swizzle pre-applied on
// the GLOBAL source (linear LDS dest), un-swizzled at ds_read (rule 21).
__global__ __launch_bounds__(256, 2) void dist_mfma(
    const ushort* __restrict__ qh, const ushort* __restrict__ qm,
    const ushort* __restrict__ ql,
    const ushort* __restrict__ eh, const ushort* __restrict__ em,
    const ushort* __restrict__ el,
    const float* __restrict__ esq,
    float* __restrict__ pval, int* __restrict__ pidx) {
    // slots of 16B: A region 3*64*8 = 1536 slots, B region 3*128*8 = 3072 slots
    __shared__ ushort tiles[4608 * 8];  // 72 KB
    __shared__ float wv[4][64];
    __shared__ int wi[4][64];
    int t = threadIdx.x;
    int w = t >> 6, lane = t & 63;
    int r0 = blockIdx.x * 64;
    int kb = blockIdx.y;        // 0..31
    int k0 = kb * 128;

    f32x4 acc[4][2];
#pragma unroll
    for (int mi = 0; mi < 4; ++mi)
#pragma unroll
        for (int ni = 0; ni < 2; ++ni) acc[mi][ni] = (f32x4){0.f, 0.f, 0.f, 0.f};

    for (int ck = 0; ck < 4; ++ck) {
        __syncthreads();
        // stage all 3 splits of A[64][64] and B[128][64] for this C-chunk
        for (int it = 0; it < 18; ++it) {
            int s = it * 256 + t;
            const ushort* g;
            if (s < 1536) {
                int a = s >> 9;
                int rem = s & 511;
                int row = rem >> 3, sr = rem & 7;
                int c = (ck << 6) + ((sr ^ (row & 7)) << 3);
                const ushort* srcp = (a == 0) ? qh : ((a == 1) ? qm : ql);
                g = srcp + (size_t)(r0 + row) * CC + c;
            } else {
                int s2 = s - 1536;
                int b2 = s2 >> 10;
                int rem = s2 & 1023;
                int row = rem >> 3, sr = rem & 7;
                int c = (ck << 6) + ((sr ^ (row & 7)) << 3);
                const ushort* srcp = (b2 == 0) ? eh : ((b2 == 1) ? em : el);
                g = srcp + (size_t)(k0 + row) * CC + c;
            }
            ushort* lb = &tiles[(size_t)(it * 256 + (w << 6)) * 8];
            __builtin_amdgcn_global_load_lds(
                (const __attribute__((address_space(1))) unsigned int*)g,
                (__attribute__((address_space(3))) unsigned int*)lb, 16, 0, 0);
        }
        __syncthreads();

        // 6 split-product passes: (a,b) with a+b<=2
#pragma unroll
        for (int p = 0; p < 6; ++p) {
            const int a = (p == 0 || p == 1 || p == 3) ? 0 : ((p == 2 || p == 4) ? 1 : 2);
            const int b = (p == 0 || p == 2 || p == 5) ? 0 : ((p == 1 || p == 4) ? 1 : 2);
#pragma unroll
            for (int kk = 0; kk < 2; ++kk) {
                int cc = (kk << 5) + ((lane >> 4) << 3);
                short8 bfr[2];
#pragma unroll
                for (int ni = 0; ni < 2; ++ni) {
                    int kcol = (w << 5) + (ni << 4) + (lane & 15);
                    int slot = 1536 + (b << 10) + (kcol << 3) + ((cc >> 3) ^ (kcol & 7));
                    bfr[ni] = *(const short8*)&tiles[slot * 8];
                }
#pragma unroll
                for (int mi = 0; mi < 4; ++mi) {
                    int row = (mi << 4) + (lane & 15);
                    int slot = (a << 9) + (row << 3) + ((cc >> 3) ^ (row & 7));
                    short8 af = *(const short8*)&tiles[slot * 8];
                    acc[mi][0] = __builtin_amdgcn_mfma_f32_16x16x32_bf16(af, bfr[0], acc[mi][0], 0, 0, 0);
                    acc[mi][1] = __builtin_amdgcn_mfma_f32_16x16x32_bf16(af, bfr[1], acc[mi][1], 0, 0, 0);
                }
            }
        }
    }

    // epilogue: score = esq - 2*dot; per-row lexicographic argmin
    int cbase = k0 + (w << 5) + (lane & 15);
    float e0 = esq[cbase];
    float e1 = esq[cbase + 16];
#pragma unroll
    for (int mi = 0; mi < 4; ++mi) {
#pragma unroll
        for (int reg = 0; reg < 4; ++reg) {
            float v = e0 - 2.f * acc[mi][0][reg];
            int i = cbase;
            float v1 = e1 - 2.f * acc[mi][1][reg];
            if (v1 < v) { v = v1; i = cbase + 16; }  // i1>i0: strict < keeps first
#pragma unroll
            for (int d = 1; d < 16; d <<= 1) {
                float ov = __shfl_xor(v, d);
                int oi = __shfl_xor(i, d);
                if (ov < v || (ov == v && oi < i)) { v = ov; i = oi; }
            }
            if ((lane & 15) == 0) {
                int rl = (mi << 4) + ((lane >> 4) << 2) + reg;
                wv[w][rl] = v;
                wi[w][rl] = i;
            }
        }
    }
    __syncthreads();
    if (t < 64) {
        float v = wv[0][t];
        int i = wi[0][t];
#pragma unroll
        for (int ww = 1; ww < 4; ++ww) {
            float ov = wv[ww][t];
            int oi = wi[ww][t];
            if (ov < v || (ov == v && oi < i)) { v = ov; i = oi; }
        }
        pval[(size_t)(r0 + t) * 32 + kb] = v;
        pidx[(size_t)(r0 + t) * 32 + kb] = i;
    }
}

// ---------------------------------------------------------------------------
// fused partial-combine + gather + interp + f_hat/f_rest update + loss partial
__global__ __launch_bounds__(256) void update_kernel(
    const float* __restrict__ emb, const float* __restrict__ pval,
    const int* __restrict__ pidx, const float* __restrict__ f,
    float* __restrict__ fhat, float* __restrict__ frest,
    float* __restrict__ parts, int pn) {
    int bn = blockIdx.x;
    int b = bn >> 10, n = bn & 1023;
    int t = threadIdx.x;
    float s = (n + 0.5f) * ((float)pn * (1.0f / 1024.0f)) - 0.5f;
    if (s < 0.f) s = 0.f;
    int i0 = (int)s;
    float wgt = s - (float)i0;
    int i1 = min(i0 + 1, pn - 1);
    __shared__ int ksel[2];
    if (t < 64) {
        int which = t >> 5;  // 0: i0 row, 1: i1 row
        int kbs = t & 31;
        int rowg = b * pn + (which ? i1 : i0);
        float v = pval[(size_t)rowg * 32 + kbs];
        int i = pidx[(size_t)rowg * 32 + kbs];
#pragma unroll
        for (int d = 1; d < 32; d <<= 1) {
            float ov = __shfl_xor(v, d);
            int oi = __shfl_xor(i, d);
            if (ov < v || (ov == v && oi < i)) { v = ov; i = oi; }
        }
        if (kbs == 0) ksel[which] = i;
    }
    __syncthreads();
    int k0 = ksel[0], k1 = ksel[1];
    float e0 = emb[(size_t)k0 * CC + t];
    float e1 = emb[(size_t)k1 * CC + t];
    float h = (1.f - wgt) * e0 + wgt * e1;
    size_t o = (size_t)bn * CC + t;
    float fh = fhat[o] + h;
    fhat[o] = fh;
    frest[o] -= h;
    float d = fh - f[o];
    float sq = d * d;
    for (int off = 32; off > 0; off >>= 1) sq += __shfl_down(sq, off);
    __shared__ float wred[4];
    if ((t & 63) == 0) wred[t >> 6] = sq;
    __syncthreads();
    if (t == 0) parts[bn] = wred[0] + wred[1] + wred[2] + wred[3];
}

// ---------------------------------------------------------------------------
__global__ void reduce_loss_all(const float* __restrict__ parts, float* __restrict__ loss) {
    __shared__ float red[256];
    int t = threadIdx.x;
    const float* p = parts + (size_t)blockIdx.x * (BB * NN);
    float s = 0.f;
    for (int i = t; i < BB * NN; i += 256) s += p[i];
    red[t] = s;
    __syncthreads();
    for (int k = 128; k > 0; k >>= 1) {
        if (t < k) red[t] += red[t + k];
        __syncthreads();
    }
    if (t == 0) loss[blockIdx.x] = red[0];
}

__global__ void finalize_kernel(const float* __restrict__ loss, float* __restrict__ out) {
    float cs = 0.f;
    for (int s = 0; s < SN; ++s) cs += loss[s];
    float mean_sum = cs / (float)BNC;
    out[BNC] = 0.25f * mean_sum / (float)SN;
    out[BNC + 1] = mean_sum / (float)SN;
}

// ---------------------------------------------------------------------------
extern "C" void kernel_launch(void* const* d_in, const int* in_sizes, int n_in,
                              void* d_out, int out_size, void* d_ws, size_t ws_size,
                              hipStream_t stream) {
    const float* f    = (const float*)d_in[0];  // [B,N,C]
    const float* base = (const float*)d_in[1];  // [K,C]
    const float* pw   = (const float*)d_in[2];  // [C,C]
    const float* pb   = (const float*)d_in[3];  // [C]
    float* out = (float*)d_out;

    float* emb   = (float*)d_ws;                 // K*C
    float* esq   = emb + (size_t)KK * CC;        // K
    float* pwT   = esq + KK;                     // C*C
    float* frest = pwT + (size_t)CC * CC;        // BNC
    float* parts = frest + BNC;                  // SN*B*N
    float* pval  = parts + (size_t)SN * BB * NN; // RMAX*32
    float* loss  = pval + (size_t)RMAX * 32;     // SN (+1 pad)
    int*   pidx  = (int*)(loss + SN + 1);        // RMAX*32
    ushort* eh = (ushort*)(pidx + (size_t)RMAX * 32);
    ushort* em = eh + (size_t)KK * CC;
    ushort* el = em + (size_t)KK * CC;
    ushort* qh = el + (size_t)KK * CC;           // RMAX*C each
    ushort* qm = qh + (size_t)RMAX * CC;
    ushort* ql = qm + (size_t)RMAX * CC;

    hipMemsetAsync(out, 0, (size_t)BNC * sizeof(float), stream);
    hipMemcpyAsync(frest, f, (size_t)BNC * sizeof(float), hipMemcpyDeviceToDevice, stream);

    transpose_pw<<<CC, CC, 0, stream>>>(pw, pwT);
    embed_kernel<<<KK / 16, 256, 0, stream>>>(base, pwT, pb, emb, eh, em, el, esq);

    for (int sidx = 0; sidx < SN; ++sidx) {
        int pn = 1 << sidx;
        int R = BB * pn;
        int rb = (R + 63) / 64;
        pool_split<<<rb * 64, 64, 0, stream>>>(frest, qh, qm, ql, pn, R);
        dist_mfma<<<dim3(rb, 32), 256, 0, stream>>>(qh, qm, ql, eh, em, el, esq, pval, pidx);
        update_kernel<<<BB * NN, 256, 0, stream>>>(emb, pval, pidx, f, out, frest,
                                                   parts + (size_t)sidx * BB * NN, pn);
    }
    reduce_loss_all<<<SN, 256, 0, stream>>>(parts, loss);
    finalize_kernel<<<1, 1, 0, stream>>>(loss, out);
}

// Round 3
// 711.534 us; speedup vs baseline: 3.6688x; 1.5751x over previous
//
#include <hip/hip_runtime.h>
#include <cfloat>

#define BB 8
#define NN 1024
#define CC 256
#define KK 4096
#define SN 11
#define BNC (BB*NN*CC)
#define RMAX 8192

typedef __attribute__((ext_vector_type(8))) short short8;
typedef __attribute__((ext_vector_type(4))) float f32x4;

__device__ __forceinline__ ushort f2bf(float f) {
    union { float f; unsigned u; } x; x.f = f;
    unsigned r = (x.u + 0x7fffu + ((x.u >> 16) & 1u)) >> 16;
    return (ushort)r;
}
__device__ __forceinline__ float bf2f(ushort b) {
    union { float f; unsigned u; } x; x.u = ((unsigned)b) << 16;
    return x.f;
}
__device__ __forceinline__ void split3(float v, ushort& h, ushort& m, ushort& l) {
    h = f2bf(v);
    float fh = bf2f(h);
    m = f2bf(v - fh);
    float fm = bf2f(m);
    l = f2bf(v - fh - fm);
}

// ---------------------------------------------------------------------------
__global__ void transpose_pw(const float* __restrict__ pw, float* __restrict__ pwT) {
    int j = blockIdx.x;
    int c = threadIdx.x;
    pwT[j * CC + c] = pw[c * CC + j];
}

// ---------------------------------------------------------------------------
// embedding = base @ proj_w.T + b ; f32 emb, 3-way bf16 splits, e_sq
__global__ __launch_bounds__(256) void embed_kernel(
    const float* __restrict__ base, const float* __restrict__ pwT,
    const float* __restrict__ pb, float* __restrict__ emb,
    ushort* __restrict__ eh, ushort* __restrict__ em, ushort* __restrict__ el,
    float* __restrict__ esq) {
    __shared__ float bs[16][CC];
    __shared__ float red[256];
    int k0 = blockIdx.x * 16;
    int t = threadIdx.x;
    for (int i = t; i < 16 * CC; i += 256) bs[i >> 8][i & 255] = base[k0 * CC + i];
    __syncthreads();
    float acc[16];
#pragma unroll
    for (int m = 0; m < 16; ++m) acc[m] = 0.f;
    for (int j = 0; j < CC; ++j) {
        float w = pwT[j * CC + t];
#pragma unroll
        for (int m = 0; m < 16; ++m) acc[m] += bs[m][j] * w;
    }
    float bias = pb[t];
    for (int m = 0; m < 16; ++m) {
        float v = acc[m] + bias;
        int o = (k0 + m) * CC + t;
        emb[o] = v;
        ushort h, md, lo;
        split3(v, h, md, lo);
        eh[o] = h; em[o] = md; el[o] = lo;
        red[t] = v * v;
        __syncthreads();
        for (int s = 128; s > 0; s >>= 1) {
            if (t < s) red[t] += red[t + s];
            __syncthreads();
        }
        if (t == 0) esq[k0 + m] = red[0];
        __syncthreads();
    }
}

// ---------------------------------------------------------------------------
// phase-A init pool: partial16[b][n16][c] = sum_{j<16} f[b][n16*16+j][c]
// grid 512 blocks x 256 threads (full GPU parallelism at every scale)
__global__ __launch_bounds__(256) void init_pool16(const float* __restrict__ f,
                                                   float* __restrict__ p16) {
    int blk = blockIdx.x;  // b*64 + n16
    int t = threadIdx.x;
    size_t base = (size_t)blk * 16 * CC + t;
    float s = 0.f;
#pragma unroll
    for (int j = 0; j < 16; ++j) s += f[base + (size_t)j * CC];
    p16[(size_t)blk * CC + t] = s;
}

// ---------------------------------------------------------------------------
// phase-B: pool partial16 sums -> q splits at scale pnn (pnn <= 64)
__global__ void poolB(const float* __restrict__ p16, ushort* __restrict__ qh,
                      ushort* __restrict__ qm, ushort* __restrict__ ql, int pnn) {
    int r = blockIdx.x;  // 0..8*pnn-1
    int b = r / pnn, p = r - b * pnn;
    int g16 = 64 / pnn;
    int c4 = threadIdx.x;  // 0..63
    const float4* src = (const float4*)(p16 + ((size_t)b * 64 + (size_t)p * g16) * CC) + c4;
    float4 s = make_float4(0.f, 0.f, 0.f, 0.f);
    for (int i = 0; i < g16; ++i) {
        float4 v = src[(size_t)i * 64];
        s.x += v.x; s.y += v.y; s.z += v.z; s.w += v.w;
    }
    float inv = 1.f / (float)(g16 * 16);
    s.x *= inv; s.y *= inv; s.z *= inv; s.w *= inv;
    ushort4 H, M, L;
    split3(s.x, H.x, M.x, L.x);
    split3(s.y, H.y, M.y, L.y);
    split3(s.z, H.z, M.z, L.z);
    split3(s.w, H.w, M.w, L.w);
    size_t o = (size_t)r * CC + 4 * c4;
    *(ushort4*)&qh[o] = H;
    *(ushort4*)&qm[o] = M;
    *(ushort4*)&ql[o] = L;
}

// ---------------------------------------------------------------------------
// MFMA distance + fused per-row argmin (unchanged from round 2).
__global__ __launch_bounds__(256, 2) void dist_mfma(
    const ushort* __restrict__ qh, const ushort* __restrict__ qm,
    const ushort* __restrict__ ql,
    const ushort* __restrict__ eh, const ushort* __restrict__ em,
    const ushort* __restrict__ el,
    const float* __restrict__ esq,
    float* __restrict__ pval, int* __restrict__ pidx) {
    __shared__ ushort tiles[4608 * 8];  // 72 KB
    __shared__ float wv[4][64];
    __shared__ int wi[4][64];
    int t = threadIdx.x;
    int w = t >> 6, lane = t & 63;
    int r0 = blockIdx.x * 64;
    int kb = blockIdx.y;
    int k0 = kb * 128;

    f32x4 acc[4][2];
#pragma unroll
    for (int mi = 0; mi < 4; ++mi)
#pragma unroll
        for (int ni = 0; ni < 2; ++ni) acc[mi][ni] = (f32x4){0.f, 0.f, 0.f, 0.f};

    for (int ck = 0; ck < 4; ++ck) {
        __syncthreads();
        for (int it = 0; it < 18; ++it) {
            int s = it * 256 + t;
            const ushort* g;
            if (s < 1536) {
                int a = s >> 9;
                int rem = s & 511;
                int row = rem >> 3, sr = rem & 7;
                int c = (ck << 6) + ((sr ^ (row & 7)) << 3);
                const ushort* srcp = (a == 0) ? qh : ((a == 1) ? qm : ql);
                g = srcp + (size_t)(r0 + row) * CC + c;
            } else {
                int s2 = s - 1536;
                int b2 = s2 >> 10;
                int rem = s2 & 1023;
                int row = rem >> 3, sr = rem & 7;
                int c = (ck << 6) + ((sr ^ (row & 7)) << 3);
                const ushort* srcp = (b2 == 0) ? eh : ((b2 == 1) ? em : el);
                g = srcp + (size_t)(k0 + row) * CC + c;
            }
            ushort* lb = &tiles[(size_t)(it * 256 + (w << 6)) * 8];
            __builtin_amdgcn_global_load_lds(
                (const __attribute__((address_space(1))) unsigned int*)g,
                (__attribute__((address_space(3))) unsigned int*)lb, 16, 0, 0);
        }
        __syncthreads();

#pragma unroll
        for (int p = 0; p < 6; ++p) {
            const int a = (p == 0 || p == 1 || p == 3) ? 0 : ((p == 2 || p == 4) ? 1 : 2);
            const int b = (p == 0 || p == 2 || p == 5) ? 0 : ((p == 1 || p == 4) ? 1 : 2);
#pragma unroll
            for (int kk = 0; kk < 2; ++kk) {
                int cc = (kk << 5) + ((lane >> 4) << 3);
                short8 bfr[2];
#pragma unroll
                for (int ni = 0; ni < 2; ++ni) {
                    int kcol = (w << 5) + (ni << 4) + (lane & 15);
                    int slot = 1536 + (b << 10) + (kcol << 3) + ((cc >> 3) ^ (kcol & 7));
                    bfr[ni] = *(const short8*)&tiles[slot * 8];
                }
#pragma unroll
                for (int mi = 0; mi < 4; ++mi) {
                    int row = (mi << 4) + (lane & 15);
                    int slot = (a << 9) + (row << 3) + ((cc >> 3) ^ (row & 7));
                    short8 af = *(const short8*)&tiles[slot * 8];
                    acc[mi][0] = __builtin_amdgcn_mfma_f32_16x16x32_bf16(af, bfr[0], acc[mi][0], 0, 0, 0);
                    acc[mi][1] = __builtin_amdgcn_mfma_f32_16x16x32_bf16(af, bfr[1], acc[mi][1], 0, 0, 0);
                }
            }
        }
    }

    int cbase = k0 + (w << 5) + (lane & 15);
    float e0 = esq[cbase];
    float e1 = esq[cbase + 16];
#pragma unroll
    for (int mi = 0; mi < 4; ++mi) {
#pragma unroll
        for (int reg = 0; reg < 4; ++reg) {
            float v = e0 - 2.f * acc[mi][0][reg];
            int i = cbase;
            float v1 = e1 - 2.f * acc[mi][1][reg];
            if (v1 < v) { v = v1; i = cbase + 16; }
#pragma unroll
            for (int d = 1; d < 16; d <<= 1) {
                float ov = __shfl_xor(v, d);
                int oi = __shfl_xor(i, d);
                if (ov < v || (ov == v && oi < i)) { v = ov; i = oi; }
            }
            if ((lane & 15) == 0) {
                int rl = (mi << 4) + ((lane >> 4) << 2) + reg;
                wv[w][rl] = v;
                wi[w][rl] = i;
            }
        }
    }
    __syncthreads();
    if (t < 64) {
        float v = wv[0][t];
        int i = wi[0][t];
#pragma unroll
        for (int ww = 1; ww < 4; ++ww) {
            float ov = wv[ww][t];
            int oi = wi[ww][t];
            if (ov < v || (ov == v && oi < i)) { v = ov; i = oi; }
        }
        pval[(size_t)(r0 + t) * 32 + kb] = v;
        pidx[(size_t)(r0 + t) * 32 + kb] = i;
    }
}

// ---------------------------------------------------------------------------
__global__ void combine_kernel(const float* __restrict__ pval, const int* __restrict__ pidx,
                               int R, int* __restrict__ idx) {
    int r = blockIdx.x * 256 + threadIdx.x;
    if (r >= R) return;
    float bv = pval[(size_t)r * 32];
    int bi = pidx[(size_t)r * 32];
    for (int s = 1; s < 32; ++s) {
        float v = pval[(size_t)r * 32 + s];
        int i = pidx[(size_t)r * 32 + s];
        if (v < bv || (v == bv && i < bi)) { bv = v; bi = i; }
    }
    idx[r] = bi;
}

// ---------------------------------------------------------------------------
// fused: gather + interp + fhat update + loss partial + NEXT-scale pooling.
// grid 512 blocks (b, n16) x 256 threads (channel).
// gn = group size of next scale (N/pn_next); 0 = no pool emission.
// gn in {1,2,4,8}: emit q splits directly; gn >= 16: emit partial16 sums.
__global__ __launch_bounds__(256) void update_pool(
    const float* __restrict__ emb, const int* __restrict__ idx,
    const float* __restrict__ f, float* __restrict__ fhat,
    float* __restrict__ parts,
    ushort* __restrict__ qh, ushort* __restrict__ qm, ushort* __restrict__ ql,
    float* __restrict__ p16u, int pn, int gn, int pnn) {
    int blk = blockIdx.x;  // b*64 + n16
    int b = blk >> 6, n16 = blk & 63;
    int t = threadIdx.x;
    int n0 = n16 * 16;
    const float scale = (float)pn * (1.0f / 1024.0f);
    float sq = 0.f;
    float pr = 0.f;
    for (int j = 0; j < 16; ++j) {
        int n = n0 + j;
        float s = (n + 0.5f) * scale - 0.5f;
        if (s < 0.f) s = 0.f;
        int i0 = (int)s;
        float w = s - (float)i0;
        int i1 = min(i0 + 1, pn - 1);
        int k0 = idx[b * pn + i0];
        int k1 = idx[b * pn + i1];
        float e0 = emb[(size_t)k0 * CC + t];
        float e1 = emb[(size_t)k1 * CC + t];
        float h = (1.f - w) * e0 + w * e1;
        size_t o = ((size_t)b * NN + n) * CC + t;
        float fh = fhat[o] + h;
        fhat[o] = fh;
        float fv = f[o];
        float d = fh - fv;
        sq += d * d;
        pr += (fv - fh);  // residual for next-scale pooling
        if (gn > 0 && gn < 16 && ((j & (gn - 1)) == (gn - 1))) {
            float mean = pr * (1.f / (float)gn);
            ushort H, M, L;
            split3(mean, H, M, L);
            size_t r = (size_t)b * pnn + (size_t)(n / gn);
            qh[r * CC + t] = H;
            qm[r * CC + t] = M;
            ql[r * CC + t] = L;
            pr = 0.f;
        }
    }
    if (gn >= 16) p16u[(size_t)blk * CC + t] = pr;
    // loss partial
    for (int off = 32; off > 0; off >>= 1) sq += __shfl_down(sq, off);
    __shared__ float wred[4];
    if ((t & 63) == 0) wred[t >> 6] = sq;
    __syncthreads();
    if (t == 0) parts[blk] = wred[0] + wred[1] + wred[2] + wred[3];
}

// ---------------------------------------------------------------------------
__global__ void reduce_loss_all(const float* __restrict__ parts, float* __restrict__ loss) {
    __shared__ float red[256];
    int t = threadIdx.x;
    const float* p = parts + (size_t)blockIdx.x * 512;
    float s = p[t] + p[t + 256];
    red[t] = s;
    __syncthreads();
    for (int k = 128; k > 0; k >>= 1) {
        if (t < k) red[t] += red[t + k];
        __syncthreads();
    }
    if (t == 0) loss[blockIdx.x] = red[0];
}

__global__ void finalize_kernel(const float* __restrict__ loss, float* __restrict__ out) {
    float cs = 0.f;
    for (int s = 0; s < SN; ++s) cs += loss[s];
    float mean_sum = cs / (float)BNC;
    out[BNC] = 0.25f * mean_sum / (float)SN;
    out[BNC + 1] = mean_sum / (float)SN;
}

// ---------------------------------------------------------------------------
extern "C" void kernel_launch(void* const* d_in, const int* in_sizes, int n_in,
                              void* d_out, int out_size, void* d_ws, size_t ws_size,
                              hipStream_t stream) {
    const float* f    = (const float*)d_in[0];
    const float* base = (const float*)d_in[1];
    const float* pw   = (const float*)d_in[2];
    const float* pb   = (const float*)d_in[3];
    float* out = (float*)d_out;

    float* emb   = (float*)d_ws;                  // K*C
    float* esq   = emb + (size_t)KK * CC;         // K
    float* pwT   = esq + KK;                      // C*C
    float* parts = pwT + (size_t)CC * CC;         // SN*512
    float* pval  = parts + (size_t)SN * 512;      // RMAX*32
    float* loss  = pval + (size_t)RMAX * 32;      // SN (+pad)
    float* p16   = loss + 16;                     // B*64*C
    float* p16u  = p16 + (size_t)BB * 64 * CC;    // B*64*C
    int*   pidx  = (int*)(p16u + (size_t)BB * 64 * CC);  // RMAX*32
    int*   idxb  = pidx + (size_t)RMAX * 32;      // RMAX
    ushort* eh = (ushort*)(idxb + RMAX);
    ushort* em = eh + (size_t)KK * CC;
    ushort* el = em + (size_t)KK * CC;
    ushort* qh = el + (size_t)KK * CC;            // RMAX*C each
    ushort* qm = qh + (size_t)RMAX * CC;
    ushort* ql = qm + (size_t)RMAX * CC;

    hipMemsetAsync(out, 0, (size_t)BNC * sizeof(float), stream);

    transpose_pw<<<CC, CC, 0, stream>>>(pw, pwT);
    embed_kernel<<<KK / 16, 256, 0, stream>>>(base, pwT, pb, emb, eh, em, el, esq);
    init_pool16<<<BB * 64, 256, 0, stream>>>(f, p16);
    poolB<<<8, 64, 0, stream>>>(p16, qh, qm, ql, 1);

    for (int sidx = 0; sidx < SN; ++sidx) {
        int pn = 1 << sidx;
        int R = BB * pn;
        int rb = (R + 63) / 64;
        dist_mfma<<<dim3(rb, 32), 256, 0, stream>>>(qh, qm, ql, eh, em, el, esq, pval, pidx);
        combine_kernel<<<(R + 255) / 256, 256, 0, stream>>>(pval, pidx, R, idxb);
        int pnn = (sidx < SN - 1) ? (pn << 1) : 0;
        int gn = pnn ? (NN / pnn) : 0;
        update_pool<<<BB * 64, 256, 0, stream>>>(emb, idxb, f, out,
                                                 parts + (size_t)sidx * 512,
                                                 qh, qm, ql, p16u, pn, gn, pnn);
        if (pnn && gn >= 16) poolB<<<BB * pnn, 64, 0, stream>>>(p16u, qh, qm, ql, pnn);
    }
    reduce_loss_all<<<SN, 256, 0, stream>>>(parts, loss);
    finalize_kernel<<<1, 1, 0, stream>>>(loss, out);
}

// Round 4
// 707.477 us; speedup vs baseline: 3.6899x; 1.0057x over previous
//
#include <hip/hip_runtime.h>
#include <cfloat>

#define BB 8
#define NN 1024
#define CC 256
#define KK 4096
#define SN 11
#define BNC (BB*NN*CC)
#define RMAX 8192

typedef __attribute__((ext_vector_type(8))) _Float16 half8;
typedef __attribute__((ext_vector_type(4))) float f32x4;

__device__ __forceinline__ void split2(float v, ushort& h, ushort& l) {
    // v is pre-scaled by 64; h+l captures ~22 mantissa bits of v
    union { _Float16 f; ushort u; } a, b;
    a.f = (_Float16)v;
    b.f = (_Float16)(v - (float)a.f);
    h = a.u; l = b.u;
}

// ---------------------------------------------------------------------------
__global__ void transpose_pw(const float* __restrict__ pw, float* __restrict__ pwT) {
    int j = blockIdx.x;
    int c = threadIdx.x;
    pwT[j * CC + c] = pw[c * CC + j];
}

// ---------------------------------------------------------------------------
// embedding = base @ proj_w.T + b ; f32 emb, f16 2-way splits of 64*emb, e_sq
__global__ __launch_bounds__(256) void embed_kernel(
    const float* __restrict__ base, const float* __restrict__ pwT,
    const float* __restrict__ pb, float* __restrict__ emb,
    ushort* __restrict__ eh, ushort* __restrict__ el, float* __restrict__ esq) {
    __shared__ float bs[16][CC];
    __shared__ float red[256];
    int k0 = blockIdx.x * 16;
    int t = threadIdx.x;
    for (int i = t; i < 16 * CC; i += 256) bs[i >> 8][i & 255] = base[k0 * CC + i];
    __syncthreads();
    float acc[16];
#pragma unroll
    for (int m = 0; m < 16; ++m) acc[m] = 0.f;
    for (int j = 0; j < CC; ++j) {
        float w = pwT[j * CC + t];
#pragma unroll
        for (int m = 0; m < 16; ++m) acc[m] += bs[m][j] * w;
    }
    float bias = pb[t];
    for (int m = 0; m < 16; ++m) {
        float v = acc[m] + bias;
        int o = (k0 + m) * CC + t;
        emb[o] = v;
        ushort h, l;
        split2(64.f * v, h, l);
        eh[o] = h; el[o] = l;
        red[t] = v * v;
        __syncthreads();
        for (int s = 128; s > 0; s >>= 1) {
            if (t < s) red[t] += red[t + s];
            __syncthreads();
        }
        if (t == 0) esq[k0 + m] = red[0];
        __syncthreads();
    }
}

// ---------------------------------------------------------------------------
// phase-A init pool: partial16[b][n16][c] = sum_{j<16} f[b][n16*16+j][c]
__global__ __launch_bounds__(256) void init_pool16(const float* __restrict__ f,
                                                   float* __restrict__ p16) {
    int blk = blockIdx.x;
    int t = threadIdx.x;
    size_t base = (size_t)blk * 16 * CC + t;
    float s = 0.f;
#pragma unroll
    for (int j = 0; j < 16; ++j) s += f[base + (size_t)j * CC];
    p16[(size_t)blk * CC + t] = s;
}

// ---------------------------------------------------------------------------
// phase-B: pool partial16 sums -> f32 q at scale pnn (pnn <= 64, VALU path)
__global__ void poolB(const float* __restrict__ p16, float* __restrict__ qf, int pnn) {
    int r = blockIdx.x;
    int b = r / pnn, p = r - b * pnn;
    int g16 = 64 / pnn;
    int c4 = threadIdx.x;
    const float4* src = (const float4*)(p16 + ((size_t)b * 64 + (size_t)p * g16) * CC) + c4;
    float4 s = make_float4(0.f, 0.f, 0.f, 0.f);
    for (int i = 0; i < g16; ++i) {
        float4 v = src[(size_t)i * 64];
        s.x += v.x; s.y += v.y; s.z += v.z; s.w += v.w;
    }
    float inv = 1.f / (float)(g16 * 16);
    s.x *= inv; s.y *= inv; s.z *= inv; s.w *= inv;
    ((float4*)(qf + (size_t)r * CC))[c4] = s;
}

// ---------------------------------------------------------------------------
// exact f32 distance+argmin for small scales (R <= 512).
// grid (64 code-blocks, ceil(R/32) row-chunks), 256 threads.
// thread (wave ws, lane j): code k0+j, rows r0c + ws + 4*ri.
__global__ __launch_bounds__(256, 4) void dist_small(
    const float* __restrict__ qf, const float* __restrict__ emb,
    const float* __restrict__ esq, int R,
    float* __restrict__ pval, int* __restrict__ pidx) {
    __shared__ float qs[32][CC];   // 32 KB
    __shared__ float es[64][33];   // padded: bank (j+c)%32
    int t = threadIdx.x;
    int ws = t >> 6, j = t & 63;
    int k0 = blockIdx.x * 64;
    int r0c = blockIdx.y * 32;
    // stage q rows (zero-pad beyond R)
    {
        int row = t >> 3, c0 = (t & 7) * 32;
        int gr = r0c + row;
#pragma unroll
        for (int i = 0; i < 8; ++i) {
            float4 v = (gr < R) ? *(const float4*)&qf[(size_t)gr * CC + c0 + 4 * i]
                                : make_float4(0.f, 0.f, 0.f, 0.f);
            *(float4*)&qs[row][c0 + 4 * i] = v;
        }
    }
    float acc[8];
#pragma unroll
    for (int ri = 0; ri < 8; ++ri) acc[ri] = 0.f;
    for (int ck = 0; ck < 8; ++ck) {
        __syncthreads();
        {
            int code = t >> 2, cb = (t & 3) * 8;
            float4 v0 = *(const float4*)&emb[(size_t)(k0 + code) * CC + ck * 32 + cb];
            float4 v1 = *(const float4*)&emb[(size_t)(k0 + code) * CC + ck * 32 + cb + 4];
            es[code][cb + 0] = v0.x; es[code][cb + 1] = v0.y;
            es[code][cb + 2] = v0.z; es[code][cb + 3] = v0.w;
            es[code][cb + 4] = v1.x; es[code][cb + 5] = v1.y;
            es[code][cb + 6] = v1.z; es[code][cb + 7] = v1.w;
        }
        __syncthreads();
        for (int c = 0; c < 32; ++c) {
            float ev = es[j][c];
#pragma unroll
            for (int ri = 0; ri < 8; ++ri)
                acc[ri] += qs[ws + 4 * ri][ck * 32 + c] * ev;
        }
    }
    float esv = esq[k0 + j];
#pragma unroll
    for (int ri = 0; ri < 8; ++ri) {
        int r = r0c + ws + 4 * ri;
        if (r >= R) continue;
        float v = esv - 2.f * acc[ri];
        int bi = k0 + j;
#pragma unroll
        for (int d = 1; d < 64; d <<= 1) {
            float ov = __shfl_xor(v, d);
            int oi = __shfl_xor(bi, d);
            if (ov < v || (ov == v && oi < bi)) { v = ov; bi = oi; }
        }
        if (j == 0) {
            pval[(size_t)r * 64 + blockIdx.x] = v;
            pidx[(size_t)r * 64 + blockIdx.x] = bi;
        }
    }
}

// ---------------------------------------------------------------------------
// MFMA distance for pn >= 128 (R multiple of 128). f16 2-split, 3 passes.
// Block: 512 threads = 8 waves (2 row-groups x 4 col-groups), tile 128x128, BK=64.
__global__ __launch_bounds__(512, 4) void dist_mfma(
    const ushort* __restrict__ qh, const ushort* __restrict__ ql,
    const ushort* __restrict__ eh, const ushort* __restrict__ el,
    const float* __restrict__ esq,
    float* __restrict__ pval, int* __restrict__ pidx) {
    // 16B slots: A region slots 0..2047 (split*1024 + row*8 + sr), B 2048..4095
    __shared__ ushort tiles[4096 * 8];  // 64 KB
    __shared__ float wv[8][64];
    __shared__ int wi[8][64];
    int t = threadIdx.x;
    int w = t >> 6, lane = t & 63;
    int wr = w >> 2, wc = w & 3;
    int r0 = blockIdx.x * 128;
    int kb = blockIdx.y;
    int k0 = kb * 128;

    f32x4 acc[4][2];
#pragma unroll
    for (int mi = 0; mi < 4; ++mi)
#pragma unroll
        for (int ni = 0; ni < 2; ++ni) acc[mi][ni] = (f32x4){0.f, 0.f, 0.f, 0.f};

    for (int ck = 0; ck < 4; ++ck) {
        __syncthreads();
#pragma unroll
        for (int it = 0; it < 8; ++it) {
            int s = it * 512 + t;
            const ushort* g;
            if (s < 2048) {
                int a = s >> 10;
                int rem = s & 1023;
                int row = rem >> 3, sr = rem & 7;
                int c = (ck << 6) + ((sr ^ (row & 7)) << 3);
                g = (a ? ql : qh) + (size_t)(r0 + row) * CC + c;
            } else {
                int s2 = s - 2048;
                int b = s2 >> 10;
                int rem = s2 & 1023;
                int kcol = rem >> 3, sr = rem & 7;
                int c = (ck << 6) + ((sr ^ (kcol & 7)) << 3);
                g = (b ? el : eh) + (size_t)(k0 + kcol) * CC + c;
            }
            ushort* lb = &tiles[(size_t)(it * 512 + (w << 6)) * 8];
            __builtin_amdgcn_global_load_lds(
                (const __attribute__((address_space(1))) unsigned int*)g,
                (__attribute__((address_space(3))) unsigned int*)lb, 16, 0, 0);
        }
        __syncthreads();

        // passes (a,b): (0,0), (0,1), (1,0)
#pragma unroll
        for (int p = 0; p < 3; ++p) {
            const int a = (p == 2) ? 1 : 0;
            const int b = (p == 1) ? 1 : 0;
#pragma unroll
            for (int kk = 0; kk < 2; ++kk) {
                int cc = (kk << 5) + ((lane >> 4) << 3);
                half8 bfr[2];
#pragma unroll
                for (int ni = 0; ni < 2; ++ni) {
                    int kcol = (wc << 5) + (ni << 4) + (lane & 15);
                    int slot = 2048 + (b << 10) + (kcol << 3) + ((cc >> 3) ^ (kcol & 7));
                    bfr[ni] = *(const half8*)&tiles[slot * 8];
                }
#pragma unroll
                for (int mi = 0; mi < 4; ++mi) {
                    int row = (wr << 6) + (mi << 4) + (lane & 15);
                    int slot = (a << 10) + (row << 3) + ((cc >> 3) ^ (row & 7));
                    half8 af = *(const half8*)&tiles[slot * 8];
                    acc[mi][0] = __builtin_amdgcn_mfma_f32_16x16x32_f16(af, bfr[0], acc[mi][0], 0, 0, 0);
                    acc[mi][1] = __builtin_amdgcn_mfma_f32_16x16x32_f16(af, bfr[1], acc[mi][1], 0, 0, 0);
                }
            }
        }
    }

    // epilogue: score = 4096*esq - 2*dot(64q,64e); per-row lexicographic argmin
    int cbase = k0 + (wc << 5) + (lane & 15);
    float e0 = 4096.f * esq[cbase];
    float e1 = 4096.f * esq[cbase + 16];
#pragma unroll
    for (int mi = 0; mi < 4; ++mi) {
#pragma unroll
        for (int reg = 0; reg < 4; ++reg) {
            float v = e0 - 2.f * acc[mi][0][reg];
            int i = cbase;
            float v1 = e1 - 2.f * acc[mi][1][reg];
            if (v1 < v) { v = v1; i = cbase + 16; }
#pragma unroll
            for (int d = 1; d < 16; d <<= 1) {
                float ov = __shfl_xor(v, d);
                int oi = __shfl_xor(i, d);
                if (ov < v || (ov == v && oi < i)) { v = ov; i = oi; }
            }
            if ((lane & 15) == 0) {
                int r64 = (mi << 4) + ((lane >> 4) << 2) + reg;
                wv[w][r64] = v;
                wi[w][r64] = i;
            }
        }
    }
    __syncthreads();
    if (t < 128) {
        int wr2 = t >> 6, r64 = t & 63;
        float v = wv[wr2 * 4][r64];
        int i = wi[wr2 * 4][r64];
#pragma unroll
        for (int ww = 1; ww < 4; ++ww) {
            float ov = wv[wr2 * 4 + ww][r64];
            int oi = wi[wr2 * 4 + ww][r64];
            if (ov < v || (ov == v && oi < i)) { v = ov; i = oi; }
        }
        int row = wr2 * 64 + r64;
        pval[(size_t)(r0 + row) * 64 + kb] = v;
        pidx[(size_t)(r0 + row) * 64 + kb] = i;
    }
}

// ---------------------------------------------------------------------------
__global__ void combine_kernel(const float* __restrict__ pval, const int* __restrict__ pidx,
                               int R, int ks, int* __restrict__ idx) {
    int r = blockIdx.x * 256 + threadIdx.x;
    if (r >= R) return;
    float bv = pval[(size_t)r * 64];
    int bi = pidx[(size_t)r * 64];
    for (int s = 1; s < ks; ++s) {
        float v = pval[(size_t)r * 64 + s];
        int i = pidx[(size_t)r * 64 + s];
        if (v < bv || (v == bv && i < bi)) { bv = v; bi = i; }
    }
    idx[r] = bi;
}

// ---------------------------------------------------------------------------
// fused: gather + interp + fhat update + loss partial + NEXT-scale pooling.
// gn >= 16: emit partial16 sums (-> poolB -> qf). gn in {1,2,4,8}: emit f16 splits.
__global__ __launch_bounds__(256) void update_pool(
    const float* __restrict__ emb, const int* __restrict__ idx,
    const float* __restrict__ f, float* __restrict__ fhat,
    float* __restrict__ parts,
    ushort* __restrict__ qh, ushort* __restrict__ ql,
    float* __restrict__ p16u, int pn, int gn, int pnn) {
    int blk = blockIdx.x;
    int b = blk >> 6, n16 = blk & 63;
    int t = threadIdx.x;
    int n0 = n16 * 16;
    const float scale = (float)pn * (1.0f / 1024.0f);
    float sq = 0.f;
    float pr = 0.f;
    for (int j = 0; j < 16; ++j) {
        int n = n0 + j;
        float s = (n + 0.5f) * scale - 0.5f;
        if (s < 0.f) s = 0.f;
        int i0 = (int)s;
        float w = s - (float)i0;
        int i1 = min(i0 + 1, pn - 1);
        int k0 = idx[b * pn + i0];
        int k1 = idx[b * pn + i1];
        float e0 = emb[(size_t)k0 * CC + t];
        float e1 = emb[(size_t)k1 * CC + t];
        float h = (1.f - w) * e0 + w * e1;
        size_t o = ((size_t)b * NN + n) * CC + t;
        float fh = fhat[o] + h;
        fhat[o] = fh;
        float fv = f[o];
        float d = fh - fv;
        sq += d * d;
        pr += (fv - fh);
        if (gn > 0 && gn < 16 && ((j & (gn - 1)) == (gn - 1))) {
            float mean = pr * (1.f / (float)gn);
            ushort H, L;
            split2(64.f * mean, H, L);
            size_t r = (size_t)b * pnn + (size_t)(n / gn);
            qh[r * CC + t] = H;
            ql[r * CC + t] = L;
            pr = 0.f;
        }
    }
    if (gn >= 16) p16u[(size_t)blk * CC + t] = pr;
    for (int off = 32; off > 0; off >>= 1) sq += __shfl_down(sq, off);
    __shared__ float wred[4];
    if ((t & 63) == 0) wred[t >> 6] = sq;
    __syncthreads();
    if (t == 0) parts[blk] = wred[0] + wred[1] + wred[2] + wred[3];
}

// ---------------------------------------------------------------------------
__global__ void reduce_loss_all(const float* __restrict__ parts, float* __restrict__ loss) {
    __shared__ float red[256];
    int t = threadIdx.x;
    const float* p = parts + (size_t)blockIdx.x * 512;
    float s = p[t] + p[t + 256];
    red[t] = s;
    __syncthreads();
    for (int k = 128; k > 0; k >>= 1) {
        if (t < k) red[t] += red[t + k];
        __syncthreads();
    }
    if (t == 0) loss[blockIdx.x] = red[0];
}

__global__ void finalize_kernel(const float* __restrict__ loss, float* __restrict__ out) {
    float cs = 0.f;
    for (int s = 0; s < SN; ++s) cs += loss[s];
    float mean_sum = cs / (float)BNC;
    out[BNC] = 0.25f * mean_sum / (float)SN;
    out[BNC + 1] = mean_sum / (float)SN;
}

// ---------------------------------------------------------------------------
extern "C" void kernel_launch(void* const* d_in, const int* in_sizes, int n_in,
                              void* d_out, int out_size, void* d_ws, size_t ws_size,
                              hipStream_t stream) {
    const float* f    = (const float*)d_in[0];
    const float* base = (const float*)d_in[1];
    const float* pw   = (const float*)d_in[2];
    const float* pb   = (const float*)d_in[3];
    float* out = (float*)d_out;

    float* emb   = (float*)d_ws;                    // K*C
    float* esq   = emb + (size_t)KK * CC;           // K
    float* pwT   = esq + KK;                        // C*C
    float* parts = pwT + (size_t)CC * CC;           // SN*512
    float* pval  = parts + (size_t)SN * 512;        // RMAX*64
    float* loss  = pval + (size_t)RMAX * 64;        // 16
    float* p16   = loss + 16;                       // B*64*C
    float* p16u  = p16 + (size_t)BB * 64 * CC;      // B*64*C
    float* qf    = p16u + (size_t)BB * 64 * CC;     // 512*C
    int*   pidx  = (int*)(qf + (size_t)512 * CC);   // RMAX*64
    int*   idxb  = pidx + (size_t)RMAX * 64;        // RMAX
    ushort* eh = (ushort*)(idxb + RMAX);            // K*C
    ushort* el = eh + (size_t)KK * CC;              // K*C
    ushort* qh = el + (size_t)KK * CC;              // RMAX*C
    ushort* ql = qh + (size_t)RMAX * CC;            // RMAX*C

    hipMemsetAsync(out, 0, (size_t)BNC * sizeof(float), stream);

    transpose_pw<<<CC, CC, 0, stream>>>(pw, pwT);
    embed_kernel<<<KK / 16, 256, 0, stream>>>(base, pwT, pb, emb, eh, el, esq);
    init_pool16<<<BB * 64, 256, 0, stream>>>(f, p16);
    poolB<<<8, 64, 0, stream>>>(p16, qf, 1);

    for (int sidx = 0; sidx < SN; ++sidx) {
        int pn = 1 << sidx;
        int R = BB * pn;
        if (pn <= 64) {
            dim3 grid(64, (R + 31) / 32);
            dist_small<<<grid, 256, 0, stream>>>(qf, emb, esq, R, pval, pidx);
            combine_kernel<<<(R + 255) / 256, 256, 0, stream>>>(pval, pidx, R, 64, idxb);
        } else {
            int rb = R / 128;
            dist_mfma<<<dim3(rb, 32), 512, 0, stream>>>(qh, ql, eh, el, esq, pval, pidx);
            combine_kernel<<<(R + 255) / 256, 256, 0, stream>>>(pval, pidx, R, 32, idxb);
        }
        int pnn = (sidx < SN - 1) ? (pn << 1) : 0;
        int gn = pnn ? (NN / pnn) : 0;
        update_pool<<<BB * 64, 256, 0, stream>>>(emb, idxb, f, out,
                                                 parts + (size_t)sidx * 512,
                                                 qh, ql, p16u, pn, gn, pnn);
        if (pnn && gn >= 16) poolB<<<BB * pnn, 64, 0, stream>>>(p16u, qf, pnn);
    }
    reduce_loss_all<<<SN, 256, 0, stream>>>(parts, loss);
    finalize_kernel<<<1, 1, 0, stream>>>(loss, out);
}

// Round 5
// 560.915 us; speedup vs baseline: 4.6540x; 1.2613x over previous
//
#include <hip/hip_runtime.h>
#include <cfloat>

#define BB 8
#define NN 1024
#define CC 256
#define KK 4096
#define SN 11
#define BNC (BB*NN*CC)
#define RMAX 8192

typedef __attribute__((ext_vector_type(8))) _Float16 half8;
typedef __attribute__((ext_vector_type(4))) float f32x4;

__device__ __forceinline__ void split2(float v, ushort& h, ushort& l) {
    union { _Float16 f; ushort u; } a, b;
    a.f = (_Float16)v;
    b.f = (_Float16)(v - (float)a.f);
    h = a.u; l = b.u;
}

// ---------------------------------------------------------------------------
__global__ void transpose_pw(const float* __restrict__ pw, float* __restrict__ pwT) {
    int j = blockIdx.x;
    int c = threadIdx.x;
    pwT[j * CC + c] = pw[c * CC + j];
}

// ---------------------------------------------------------------------------
// embedding = base @ proj_w.T + b ; f32 emb, f16 2-way splits of 64*emb, e_sq
__global__ __launch_bounds__(256) void embed_kernel(
    const float* __restrict__ base, const float* __restrict__ pwT,
    const float* __restrict__ pb, float* __restrict__ emb,
    ushort* __restrict__ eh, ushort* __restrict__ el, float* __restrict__ esq) {
    __shared__ float bs[16][CC];
    __shared__ float wpart[16][4];
    int k0 = blockIdx.x * 16;
    int t = threadIdx.x;
    int w = t >> 6, lane = t & 63;
    for (int i = t; i < 16 * CC; i += 256) bs[i >> 8][i & 255] = base[k0 * CC + i];
    __syncthreads();
    float acc[16];
#pragma unroll
    for (int m = 0; m < 16; ++m) acc[m] = 0.f;
    for (int j = 0; j < CC; ++j) {
        float wv = pwT[j * CC + t];
#pragma unroll
        for (int m = 0; m < 16; ++m) acc[m] += bs[m][j] * wv;
    }
    float bias = pb[t];
#pragma unroll
    for (int m = 0; m < 16; ++m) {
        float v = acc[m] + bias;
        int o = (k0 + m) * CC + t;
        emb[o] = v;
        ushort h, l;
        split2(64.f * v, h, l);
        eh[o] = h; el[o] = l;
        float sq = v * v;
#pragma unroll
        for (int d = 1; d < 64; d <<= 1) sq += __shfl_xor(sq, d);
        if (lane == 0) wpart[m][w] = sq;
    }
    __syncthreads();
    if (t < 16) esq[k0 + t] = wpart[t][0] + wpart[t][1] + wpart[t][2] + wpart[t][3];
}

// ---------------------------------------------------------------------------
__global__ __launch_bounds__(256) void init_pool16(const float* __restrict__ f,
                                                   float* __restrict__ p16) {
    int blk = blockIdx.x;
    int t = threadIdx.x;
    size_t base = (size_t)blk * 16 * CC + t;
    float s = 0.f;
#pragma unroll
    for (int j = 0; j < 16; ++j) s += f[base + (size_t)j * CC];
    p16[(size_t)blk * CC + t] = s;
}

// ---------------------------------------------------------------------------
// pool partial16 sums -> f32 q at scale pnn (pnn <= 32 here)
__global__ void poolB(const float* __restrict__ p16, float* __restrict__ qf, int pnn) {
    int r = blockIdx.x;
    int b = r / pnn, p = r - b * pnn;
    int g16 = 64 / pnn;
    int c4 = threadIdx.x;
    const float4* src = (const float4*)(p16 + ((size_t)b * 64 + (size_t)p * g16) * CC) + c4;
    float4 s = make_float4(0.f, 0.f, 0.f, 0.f);
    for (int i = 0; i < g16; ++i) {
        float4 v = src[(size_t)i * 64];
        s.x += v.x; s.y += v.y; s.z += v.z; s.w += v.w;
    }
    float inv = 1.f / (float)(g16 * 16);
    s.x *= inv; s.y *= inv; s.z *= inv; s.w *= inv;
    ((float4*)(qf + (size_t)r * CC))[c4] = s;
}

// ---------------------------------------------------------------------------
// exact f32 distance+argmin for small scales (R <= 512).
__global__ __launch_bounds__(256, 4) void dist_small(
    const float* __restrict__ qf, const float* __restrict__ emb,
    const float* __restrict__ esq, int R,
    float* __restrict__ pval, int* __restrict__ pidx) {
    __shared__ float qs[32][CC];
    __shared__ float es[64][33];
    int t = threadIdx.x;
    int ws = t >> 6, j = t & 63;
    int k0 = blockIdx.x * 64;
    int r0c = blockIdx.y * 32;
    {
        int row = t >> 3, c0 = (t & 7) * 32;
        int gr = r0c + row;
#pragma unroll
        for (int i = 0; i < 8; ++i) {
            float4 v = (gr < R) ? *(const float4*)&qf[(size_t)gr * CC + c0 + 4 * i]
                                : make_float4(0.f, 0.f, 0.f, 0.f);
            *(float4*)&qs[row][c0 + 4 * i] = v;
        }
    }
    float acc[8];
#pragma unroll
    for (int ri = 0; ri < 8; ++ri) acc[ri] = 0.f;
    for (int ck = 0; ck < 8; ++ck) {
        __syncthreads();
        {
            int code = t >> 2, cb = (t & 3) * 8;
            float4 v0 = *(const float4*)&emb[(size_t)(k0 + code) * CC + ck * 32 + cb];
            float4 v1 = *(const float4*)&emb[(size_t)(k0 + code) * CC + ck * 32 + cb + 4];
            es[code][cb + 0] = v0.x; es[code][cb + 1] = v0.y;
            es[code][cb + 2] = v0.z; es[code][cb + 3] = v0.w;
            es[code][cb + 4] = v1.x; es[code][cb + 5] = v1.y;
            es[code][cb + 6] = v1.z; es[code][cb + 7] = v1.w;
        }
        __syncthreads();
        for (int c = 0; c < 32; ++c) {
            float ev = es[j][c];
#pragma unroll
            for (int ri = 0; ri < 8; ++ri)
                acc[ri] += qs[ws + 4 * ri][ck * 32 + c] * ev;
        }
    }
    float esv = esq[k0 + j];
#pragma unroll
    for (int ri = 0; ri < 8; ++ri) {
        int r = r0c + ws + 4 * ri;
        if (r >= R) continue;
        float v = esv - 2.f * acc[ri];
        int bi = k0 + j;
#pragma unroll
        for (int d = 1; d < 64; d <<= 1) {
            float ov = __shfl_xor(v, d);
            int oi = __shfl_xor(bi, d);
            if (ov < v || (ov == v && oi < bi)) { v = ov; bi = oi; }
        }
        if (j == 0) {
            pval[(size_t)r * 64 + blockIdx.x] = v;
            pidx[(size_t)r * 64 + blockIdx.x] = bi;
        }
    }
}

// ---------------------------------------------------------------------------
// MFMA distance, pn >= 128. f16 2-split, 3 passes (hh,hl,lh).
// 256 threads = 4 waves in 2x2 grid; wave tile 64x64 (mi=4, ni=4); block 128x128.
// Frags register-cached across passes: 32 ds_read_b128 feed 96 MFMA per chunk.
__global__ __launch_bounds__(256, 2) void dist_mfma(
    const ushort* __restrict__ qh, const ushort* __restrict__ ql,
    const ushort* __restrict__ eh, const ushort* __restrict__ el,
    const float* __restrict__ esq,
    float* __restrict__ pval, int* __restrict__ pidx) {
    // 16B slots: A = split*1024 + row*8 + sr ; B = 2048 + split*1024 + kcol*8 + sr
    __shared__ ushort tiles[4096 * 8];  // 64 KB
    __shared__ float wv[2][128];
    __shared__ int wi[2][128];
    int t = threadIdx.x;
    int w = t >> 6, lane = t & 63;
    int l15 = lane & 15, hi = lane >> 4;
    int wr = w >> 1, wc = w & 1;
    int r0 = blockIdx.x * 128;
    int kb = blockIdx.y;
    int k0 = kb * 128;

    f32x4 acc[4][4];
#pragma unroll
    for (int mi = 0; mi < 4; ++mi)
#pragma unroll
        for (int ni = 0; ni < 4; ++ni) acc[mi][ni] = (f32x4){0.f, 0.f, 0.f, 0.f};

    for (int ck = 0; ck < 4; ++ck) {
        __syncthreads();
#pragma unroll
        for (int it = 0; it < 16; ++it) {
            int s = it * 256 + t;
            const ushort* g;
            if (s < 2048) {
                int a = s >> 10;
                int rem = s & 1023;
                int row = rem >> 3, sr = rem & 7;
                int c = (ck << 6) + ((sr ^ (row & 7)) << 3);
                g = (a ? ql : qh) + (size_t)(r0 + row) * CC + c;
            } else {
                int s2 = s - 2048;
                int b = s2 >> 10;
                int rem = s2 & 1023;
                int kcol = rem >> 3, sr = rem & 7;
                int c = (ck << 6) + ((sr ^ (kcol & 7)) << 3);
                g = (b ? el : eh) + (size_t)(k0 + kcol) * CC + c;
            }
            ushort* lb = &tiles[(size_t)(it * 256 + (w << 6)) * 8];
            __builtin_amdgcn_global_load_lds(
                (const __attribute__((address_space(1))) unsigned int*)g,
                (__attribute__((address_space(3))) unsigned int*)lb, 16, 0, 0);
        }
        __syncthreads();

#pragma unroll
        for (int kk = 0; kk < 2; ++kk) {
            int cs = (kk << 2) + hi;  // 16B-slot column within the 64-col chunk
            half8 bf0[4], bf1[4], af[4];
#pragma unroll
            for (int ni = 0; ni < 4; ++ni) {
                int kcol = (wc << 6) + (ni << 4) + l15;
                int sb = 2048 + (kcol << 3) + (cs ^ (kcol & 7));
                bf0[ni] = *(const half8*)&tiles[sb * 8];
                bf1[ni] = *(const half8*)&tiles[(sb + 1024) * 8];
            }
#pragma unroll
            for (int mi = 0; mi < 4; ++mi) {
                int row = (wr << 6) + (mi << 4) + l15;
                af[mi] = *(const half8*)&tiles[((row << 3) + (cs ^ (row & 7))) * 8];
            }
#pragma unroll
            for (int mi = 0; mi < 4; ++mi)
#pragma unroll
                for (int ni = 0; ni < 4; ++ni)
                    acc[mi][ni] = __builtin_amdgcn_mfma_f32_16x16x32_f16(af[mi], bf0[ni], acc[mi][ni], 0, 0, 0);
#pragma unroll
            for (int mi = 0; mi < 4; ++mi)
#pragma unroll
                for (int ni = 0; ni < 4; ++ni)
                    acc[mi][ni] = __builtin_amdgcn_mfma_f32_16x16x32_f16(af[mi], bf1[ni], acc[mi][ni], 0, 0, 0);
#pragma unroll
            for (int mi = 0; mi < 4; ++mi) {
                int row = (wr << 6) + (mi << 4) + l15;
                af[mi] = *(const half8*)&tiles[(1024 + (row << 3) + (cs ^ (row & 7))) * 8];
            }
#pragma unroll
            for (int mi = 0; mi < 4; ++mi)
#pragma unroll
                for (int ni = 0; ni < 4; ++ni)
                    acc[mi][ni] = __builtin_amdgcn_mfma_f32_16x16x32_f16(af[mi], bf0[ni], acc[mi][ni], 0, 0, 0);
        }
    }

    // epilogue: score = 4096*esq - 2*dot(64q,64e); per-row lexicographic argmin
    int cbase = k0 + (wc << 6) + l15;
    float es4[4];
#pragma unroll
    for (int ni = 0; ni < 4; ++ni) es4[ni] = 4096.f * esq[cbase + ni * 16];
#pragma unroll
    for (int mi = 0; mi < 4; ++mi) {
#pragma unroll
        for (int reg = 0; reg < 4; ++reg) {
            float v = es4[0] - 2.f * acc[mi][0][reg];
            int i = cbase;
#pragma unroll
            for (int ni = 1; ni < 4; ++ni) {
                float v1 = es4[ni] - 2.f * acc[mi][ni][reg];
                if (v1 < v) { v = v1; i = cbase + ni * 16; }  // ascending k: strict <
            }
#pragma unroll
            for (int d = 1; d < 16; d <<= 1) {
                float ov = __shfl_xor(v, d);
                int oi = __shfl_xor(i, d);
                if (ov < v || (ov == v && oi < i)) { v = ov; i = oi; }
            }
            if (l15 == 0) {
                int row = (wr << 6) + (mi << 4) + (hi << 2) + reg;
                wv[wc][row] = v;
                wi[wc][row] = i;
            }
        }
    }
    __syncthreads();
    if (t < 128) {
        float v = wv[0][t];
        int i = wi[0][t];
        float ov = wv[1][t];
        int oi = wi[1][t];
        if (ov < v || (ov == v && oi < i)) { v = ov; i = oi; }
        pval[(size_t)(r0 + t) * 64 + kb] = v;
        pidx[(size_t)(r0 + t) * 64 + kb] = i;
    }
}

// ---------------------------------------------------------------------------
// fused: per-row partial-argmin combine + gather + interp + fhat update +
// loss partial + NEXT-scale pooling.
__global__ __launch_bounds__(256) void update_pool(
    const float* __restrict__ emb, const float* __restrict__ pval,
    const int* __restrict__ pidx, const float* __restrict__ f,
    float* __restrict__ fhat, float* __restrict__ parts,
    ushort* __restrict__ qh, ushort* __restrict__ ql,
    float* __restrict__ qf, float* __restrict__ p16u,
    int pn, int gn, int pnn, int ks) {
    int blk = blockIdx.x;
    int b = blk >> 6, n16 = blk & 63;
    int t = threadIdx.x;
    int w = t >> 6, lane = t & 63;
    int n0 = n16 * 16;
    const float scale = (float)pn * (1.0f / 1024.0f);
    // row range this block needs
    float s_lo = (n0 + 0.5f) * scale - 0.5f;
    if (s_lo < 0.f) s_lo = 0.f;
    int r_lo = (int)s_lo;
    float s_hi = (n0 + 15.5f) * scale - 0.5f;
    if (s_hi < 0.f) s_hi = 0.f;
    int r_hi = min((int)s_hi + 1, pn - 1);
    int cnt = r_hi - r_lo + 1;  // <= 18
    __shared__ int sidx[20];
    for (int ri = w; ri < cnt; ri += 4) {
        size_t rowg = (size_t)(b * pn + r_lo + ri) * 64;
        float v = (lane < ks) ? pval[rowg + lane] : FLT_MAX;
        int i = (lane < ks) ? pidx[rowg + lane] : 0x7fffffff;
#pragma unroll
        for (int d = 1; d < 64; d <<= 1) {
            float ov = __shfl_xor(v, d);
            int oi = __shfl_xor(i, d);
            if (ov < v || (ov == v && oi < i)) { v = ov; i = oi; }
        }
        if (lane == 0) sidx[ri] = i;
    }
    __syncthreads();
    float sq = 0.f;
    float pr = 0.f;
    for (int j = 0; j < 16; ++j) {
        int n = n0 + j;
        float s = (n + 0.5f) * scale - 0.5f;
        if (s < 0.f) s = 0.f;
        int i0 = (int)s;
        float wgt = s - (float)i0;
        int i1 = min(i0 + 1, pn - 1);
        int k0 = sidx[i0 - r_lo];
        int k1 = sidx[i1 - r_lo];
        float e0 = emb[(size_t)k0 * CC + t];
        float e1 = emb[(size_t)k1 * CC + t];
        float h = (1.f - wgt) * e0 + wgt * e1;
        size_t o = ((size_t)b * NN + n) * CC + t;
        float fh = fhat[o] + h;
        fhat[o] = fh;
        float fv = f[o];
        float d = fh - fv;
        sq += d * d;
        pr += (fv - fh);
        if (gn > 0 && gn < 16 && ((j & (gn - 1)) == (gn - 1))) {
            float mean = pr * (1.f / (float)gn);
            ushort H, L;
            split2(64.f * mean, H, L);
            size_t r = (size_t)b * pnn + (size_t)(n / gn);
            qh[r * CC + t] = H;
            ql[r * CC + t] = L;
            pr = 0.f;
        }
    }
    if (gn == 16) qf[(size_t)blk * CC + t] = pr * (1.f / 16.f);
    else if (gn >= 32) p16u[(size_t)blk * CC + t] = pr;
    for (int off = 32; off > 0; off >>= 1) sq += __shfl_down(sq, off);
    __shared__ float wred[4];
    if (lane == 0) wred[w] = sq;
    __syncthreads();
    if (t == 0) parts[blk] = wred[0] + wred[1] + wred[2] + wred[3];
}

// ---------------------------------------------------------------------------
// single deterministic reduce over all scales' partials -> commit, qlat
__global__ void reduce_final(const float* __restrict__ parts, float* __restrict__ out) {
    __shared__ float red[256];
    int t = threadIdx.x;
    float s = 0.f;
    for (int i = t; i < SN * 512; i += 256) s += parts[i];
    red[t] = s;
    __syncthreads();
    for (int k = 128; k > 0; k >>= 1) {
        if (t < k) red[t] += red[t + k];
        __syncthreads();
    }
    if (t == 0) {
        float mean_sum = red[0] / (float)BNC;
        out[BNC] = 0.25f * mean_sum / (float)SN;
        out[BNC + 1] = mean_sum / (float)SN;
    }
}

// ---------------------------------------------------------------------------
extern "C" void kernel_launch(void* const* d_in, const int* in_sizes, int n_in,
                              void* d_out, int out_size, void* d_ws, size_t ws_size,
                              hipStream_t stream) {
    const float* f    = (const float*)d_in[0];
    const float* base = (const float*)d_in[1];
    const float* pw   = (const float*)d_in[2];
    const float* pb   = (const float*)d_in[3];
    float* out = (float*)d_out;

    float* emb   = (float*)d_ws;                    // K*C
    float* esq   = emb + (size_t)KK * CC;           // K
    float* pwT   = esq + KK;                        // C*C
    float* parts = pwT + (size_t)CC * CC;           // SN*512
    float* pval  = parts + (size_t)SN * 512;        // RMAX*64
    float* p16   = pval + (size_t)RMAX * 64;        // B*64*C
    float* p16u  = p16 + (size_t)BB * 64 * CC;      // B*64*C
    float* qf    = p16u + (size_t)BB * 64 * CC;     // 512*C
    int*   pidx  = (int*)(qf + (size_t)512 * CC);   // RMAX*64
    ushort* eh = (ushort*)(pidx + (size_t)RMAX * 64);  // K*C
    ushort* el = eh + (size_t)KK * CC;              // K*C
    ushort* qh = el + (size_t)KK * CC;              // RMAX*C
    ushort* ql = qh + (size_t)RMAX * CC;            // RMAX*C

    hipMemsetAsync(out, 0, (size_t)BNC * sizeof(float), stream);

    transpose_pw<<<CC, CC, 0, stream>>>(pw, pwT);
    embed_kernel<<<KK / 16, 256, 0, stream>>>(base, pwT, pb, emb, eh, el, esq);
    init_pool16<<<BB * 64, 256, 0, stream>>>(f, p16);
    poolB<<<8, 64, 0, stream>>>(p16, qf, 1);

    for (int sidx = 0; sidx < SN; ++sidx) {
        int pn = 1 << sidx;
        int R = BB * pn;
        int ks;
        if (pn <= 64) {
            dim3 grid(64, (R + 31) / 32);
            dist_small<<<grid, 256, 0, stream>>>(qf, emb, esq, R, pval, pidx);
            ks = 64;
        } else {
            dist_mfma<<<dim3(R / 128, 32), 256, 0, stream>>>(qh, ql, eh, el, esq, pval, pidx);
            ks = 32;
        }
        int pnn = (sidx < SN - 1) ? (pn << 1) : 0;
        int gn = pnn ? (NN / pnn) : 0;
        update_pool<<<BB * 64, 256, 0, stream>>>(emb, pval, pidx, f, out,
                                                 parts + (size_t)sidx * 512,
                                                 qh, ql, qf, p16u, pn, gn, pnn, ks);
        if (pnn && gn >= 32) poolB<<<BB * pnn, 64, 0, stream>>>(p16u, qf, pnn);
    }
    reduce_final<<<1, 256, 0, stream>>>(parts, out);
}